// Round 4
// baseline (222.904 us; speedup 1.0000x reference)
//
#include <hip/hip_runtime.h>
#include <hip/hip_bf16.h>

#define BATCH 2
#define SEQ 2048
#define DMODEL 1024
#define NHEADS 16
#define HDIM 64

// 0.125 (1/sqrt(64)) * log2(e) so QK^T logits land directly in exp2 domain
#define QSCALE 0.180336880f

typedef __bf16 bf16x8 __attribute__((ext_vector_type(8)));
typedef __bf16 bf16x4 __attribute__((ext_vector_type(4)));
typedef float f32x4 __attribute__((ext_vector_type(4)));

// ---------------------------------------------------------------------------
// Flash attention: one block = 128 q-rows of one (b,h); 8 waves x 16 q-rows.
// K-chunks of 32 keys. bf16 MFMA 16x16x32. Online softmax in fp32.
// Output: bf16 attention output (B,S,D) into workspace.
// ---------------------------------------------------------------------------
__global__ __launch_bounds__(512)
void attn_kernel(const float* __restrict__ Q, const float* __restrict__ K,
                 const float* __restrict__ V, __bf16* __restrict__ O) {
  const int b = blockIdx.z, h = blockIdx.y;
  const int q0 = blockIdx.x * 128;
  const int tid = threadIdx.x;
  const int wave = tid >> 6, lane = tid & 63;
  const int g = lane >> 4, lr = lane & 15;

  // +8 bf16 pad per row -> 2-way (free) bank aliasing on b128 column reads
  __shared__ __bf16 Kt[32][72];       // [key][dim]
  __shared__ __bf16 Vt[64][40];       // [dim][key]  (transposed)
  __shared__ __bf16 Pl[8][16][40];    // per-wave P tile [qrow][key]

  // Q fragments (pre-scaled), register-resident: wave's 16 rows
  const int qrow = q0 + wave * 16 + lr;
  const float* qptr = Q + ((size_t)(b * SEQ + qrow)) * DMODEL + h * HDIM;
  bf16x8 qf[2];
#pragma unroll
  for (int t = 0; t < 2; ++t) {
    f32x4 a = *reinterpret_cast<const f32x4*>(qptr + t * 32 + g * 8);
    f32x4 c = *reinterpret_cast<const f32x4*>(qptr + t * 32 + g * 8 + 4);
#pragma unroll
    for (int j = 0; j < 4; ++j) {
      qf[t][j]     = (__bf16)(a[j] * QSCALE);
      qf[t][4 + j] = (__bf16)(c[j] * QSCALE);
    }
  }

  float m_run[4], l_run[4];
  f32x4 oacc[4];
#pragma unroll
  for (int j = 0; j < 4; ++j) {
    m_run[j] = -1e30f; l_run[j] = 0.f;
    oacc[j] = (f32x4){0.f, 0.f, 0.f, 0.f};
  }

  const float* kbase = K + ((size_t)(b * SEQ)) * DMODEL + h * HDIM;
  const float* vbase = V + ((size_t)(b * SEQ)) * DMODEL + h * HDIM;

  const int kk_s = tid >> 4;   // key within chunk (0..31)
  const int d4_s = tid & 15;   // float4 index within 64 dims

  for (int k0 = 0; k0 < SEQ; k0 += 32) {
    __syncthreads();
    // --- stage K chunk: [32 keys][64 dims] fp32 -> bf16 ---
    {
      f32x4 kv = *reinterpret_cast<const f32x4*>(
          kbase + (size_t)(k0 + kk_s) * DMODEL + d4_s * 4);
      bf16x4 kb;
#pragma unroll
      for (int j = 0; j < 4; ++j) kb[j] = (__bf16)kv[j];
      *reinterpret_cast<bf16x4*>(&Kt[kk_s][d4_s * 4]) = kb;
    }
    // --- stage V chunk transposed: Vt[dim][key] ---
    {
      f32x4 vv = *reinterpret_cast<const f32x4*>(
          vbase + (size_t)(k0 + kk_s) * DMODEL + d4_s * 4);
#pragma unroll
      for (int j = 0; j < 4; ++j) Vt[d4_s * 4 + j][kk_s] = (__bf16)vv[j];
    }
    __syncthreads();

    // --- QK^T: two 16-key sub-chunks ---
    f32x4 sacc[2];
#pragma unroll
    for (int c = 0; c < 2; ++c) {
      bf16x8 bk0 = *reinterpret_cast<const bf16x8*>(&Kt[c * 16 + lr][g * 8]);
      bf16x8 bk1 = *reinterpret_cast<const bf16x8*>(&Kt[c * 16 + lr][32 + g * 8]);
      f32x4 acc = (f32x4){0.f, 0.f, 0.f, 0.f};
      acc = __builtin_amdgcn_mfma_f32_16x16x32_bf16(qf[0], bk0, acc, 0, 0, 0);
      acc = __builtin_amdgcn_mfma_f32_16x16x32_bf16(qf[1], bk1, acc, 0, 0, 0);
      sacc[c] = acc;
    }

    // --- online softmax; reg j <-> q-row 4g+j; 16 lanes of a group share rows ---
#pragma unroll
    for (int j = 0; j < 4; ++j) {
      float mn = fmaxf(sacc[0][j], sacc[1][j]);
#pragma unroll
      for (int msk = 1; msk < 16; msk <<= 1) mn = fmaxf(mn, __shfl_xor(mn, msk, 64));
      float mu = fmaxf(m_run[j], mn);
      float alpha = __builtin_amdgcn_exp2f(m_run[j] - mu);
      m_run[j] = mu;
      float p0 = __builtin_amdgcn_exp2f(sacc[0][j] - mu);
      float p1 = __builtin_amdgcn_exp2f(sacc[1][j] - mu);
      float ps = p0 + p1;
#pragma unroll
      for (int msk = 1; msk < 16; msk <<= 1) ps += __shfl_xor(ps, msk, 64);
      l_run[j] = l_run[j] * alpha + ps;
#pragma unroll
      for (int n = 0; n < 4; ++n) oacc[n][j] *= alpha;
      // write P (transpose via per-wave LDS): row=q-row 4g+j, col=key
      Pl[wave][g * 4 + j][lr]      = (__bf16)p0;
      Pl[wave][g * 4 + j][16 + lr] = (__bf16)p1;
    }
    // wave-synchronous LDS: drain our own ds_writes before cross-lane read
    asm volatile("s_waitcnt lgkmcnt(0)" ::: "memory");

    // --- PV: A = P (16x32), B = V chunk (32x16 per n-tile) ---
    bf16x8 pa = *reinterpret_cast<const bf16x8*>(&Pl[wave][lr][g * 8]);
#pragma unroll
    for (int n = 0; n < 4; ++n) {
      bf16x8 bv = *reinterpret_cast<const bf16x8*>(&Vt[n * 16 + lr][g * 8]);
      oacc[n] = __builtin_amdgcn_mfma_f32_16x16x32_bf16(pa, bv, oacc[n], 0, 0, 0);
    }
  }

  // --- normalize + store bf16 attention output ---
#pragma unroll
  for (int j = 0; j < 4; ++j) {
    float inv = 1.0f / l_run[j];
    int row = q0 + wave * 16 + g * 4 + j;
    __bf16* optr = O + ((size_t)(b * SEQ + row)) * DMODEL + h * HDIM;
#pragma unroll
    for (int n = 0; n < 4; ++n) optr[n * 16 + lr] = (__bf16)(oacc[n][j] * inv);
  }
}

// ---------------------------------------------------------------------------
// FC: Y[M=4096][N=1024] = X(bf16) @ W^T(fp32->bf16) + bias, fp32 out.
// 128x128 tile, 4 waves (2x2), each wave 64x64 via 4x4 16x16 fragments.
// ---------------------------------------------------------------------------
__global__ __launch_bounds__(256)
void fc_kernel(const __bf16* __restrict__ X, const float* __restrict__ W,
               const float* __restrict__ bias, float* __restrict__ Y) {
  const int n0 = blockIdx.x * 128;
  const int m0 = blockIdx.y * 128;
  const int tid = threadIdx.x;
  const int wave = tid >> 6, lane = tid & 63;
  const int g = lane >> 4, lr = lane & 15;
  const int wm = wave >> 1, wn = wave & 1;

  __shared__ __bf16 As[128][40];   // [m][k] bf16, +8 pad
  __shared__ __bf16 Bs[128][40];   // [n][k] bf16 (B = W^T staged as W rows)

  f32x4 acc[4][4];
#pragma unroll
  for (int i = 0; i < 4; ++i)
#pragma unroll
    for (int j = 0; j < 4; ++j) acc[i][j] = (f32x4){0.f, 0.f, 0.f, 0.f};

  float bv[4];
#pragma unroll
  for (int j = 0; j < 4; ++j) bv[j] = bias[n0 + wn * 64 + 16 * j + lr];

  for (int kk = 0; kk < DMODEL; kk += 32) {
    __syncthreads();
    // stage A: 128x32 bf16 from workspace
#pragma unroll
    for (int e = 0; e < 2; ++e) {
      int idx = tid + 256 * e;           // 0..511
      int row = idx >> 2, k8 = idx & 3;
      bf16x8 v = *reinterpret_cast<const bf16x8*>(
          X + (size_t)(m0 + row) * DMODEL + kk + k8 * 8);
      *reinterpret_cast<bf16x8*>(&As[row][k8 * 8]) = v;
    }
    // stage B: 128x32 fp32 W rows -> bf16
#pragma unroll
    for (int e = 0; e < 4; ++e) {
      int idx = tid + 256 * e;           // 0..1023
      int row = idx >> 3, k4 = idx & 7;
      f32x4 wv = *reinterpret_cast<const f32x4*>(
          W + (size_t)(n0 + row) * DMODEL + kk + k4 * 4);
      bf16x4 wb;
#pragma unroll
      for (int j = 0; j < 4; ++j) wb[j] = (__bf16)wv[j];
      *reinterpret_cast<bf16x4*>(&Bs[row][k4 * 4]) = wb;
    }
    __syncthreads();

    bf16x8 af[4], bfr[4];
#pragma unroll
    for (int i = 0; i < 4; ++i)
      af[i] = *reinterpret_cast<const bf16x8*>(&As[wm * 64 + 16 * i + lr][g * 8]);
#pragma unroll
    for (int j = 0; j < 4; ++j)
      bfr[j] = *reinterpret_cast<const bf16x8*>(&Bs[wn * 64 + 16 * j + lr][g * 8]);
#pragma unroll
    for (int i = 0; i < 4; ++i)
#pragma unroll
      for (int j = 0; j < 4; ++j)
        acc[i][j] = __builtin_amdgcn_mfma_f32_16x16x32_bf16(af[i], bfr[j], acc[i][j], 0, 0, 0);
  }

#pragma unroll
  for (int i = 0; i < 4; ++i) {
    int m = m0 + wm * 64 + 16 * i + g * 4;
#pragma unroll
    for (int j = 0; j < 4; ++j) {
      int n = n0 + wn * 64 + 16 * j + lr;
      float* yp = Y + (size_t)m * DMODEL + n;
#pragma unroll
      for (int r = 0; r < 4; ++r) yp[(size_t)r * DMODEL] = acc[i][j][r] + bv[j];
    }
  }
}

extern "C" void kernel_launch(void* const* d_in, const int* in_sizes, int n_in,
                              void* d_out, int out_size, void* d_ws, size_t ws_size,
                              hipStream_t stream) {
  const float* q    = (const float*)d_in[0];
  const float* k    = (const float*)d_in[1];
  const float* v    = (const float*)d_in[2];
  const float* w    = (const float*)d_in[3];
  const float* bias = (const float*)d_in[4];
  float* out = (float*)d_out;
  __bf16* O = (__bf16*)d_ws;   // 4096*1024 bf16 = 8 MB attention output

  dim3 gridA(SEQ / 128, NHEADS, BATCH);
  attn_kernel<<<gridA, 512, 0, stream>>>(q, k, v, O);

  dim3 gridF(DMODEL / 128, (BATCH * SEQ) / 128);
  fc_kernel<<<gridF, 256, 0, stream>>>(O, w, bias, out);
}

// Round 5
// 142.956 us; speedup vs baseline: 1.5593x; 1.5593x over previous
//
#include <hip/hip_runtime.h>
#include <hip/hip_bf16.h>

#define BATCH 2
#define SEQ 2048
#define DMODEL 1024
#define NHEADS 16
#define HDIM 64
#define KVBLK 64
#define NCHUNK (SEQ / KVBLK)   // 32

// 0.125 (1/sqrt(64)) * log2(e) so QK^T logits land directly in exp2 domain
#define QSCALE 0.180336880f

typedef __bf16 bf16x8 __attribute__((ext_vector_type(8)));
typedef __bf16 bf16x4 __attribute__((ext_vector_type(4)));
typedef float f32x4 __attribute__((ext_vector_type(4)));

// ---------------------------------------------------------------------------
// Flash attention: one block = 128 q-rows of one (b,h); 8 waves x 16 q-rows.
// KVBLK=64 chunks, double-buffered LDS, single barrier per chunk, loads for
// chunk c+1 issued before compute of chunk c (latency hiding).
// ---------------------------------------------------------------------------
__global__ __launch_bounds__(512)
void attn_kernel(const float* __restrict__ Q, const float* __restrict__ K,
                 const float* __restrict__ V, __bf16* __restrict__ O) {
  const int b = blockIdx.z, h = blockIdx.y;
  const int q0 = blockIdx.x * 128;
  const int tid = threadIdx.x;
  const int wave = tid >> 6, lane = tid & 63;
  const int g = lane >> 4, lr = lane & 15;

  // rows padded to 72 bf16 (144 B) -> b128 reads stay 16B-aligned
  __shared__ __bf16 Ks[2][KVBLK][72];   // [buf][key][dim]
  __shared__ __bf16 Vt[2][HDIM][72];    // [buf][dim][key] (transposed)
  __shared__ __bf16 Pl[8][16][40];      // per-wave P tile [qrow][key-half]

  // Q fragments (pre-scaled), register-resident: wave's 16 rows
  const int qrow = q0 + wave * 16 + lr;
  const float* qptr = Q + ((size_t)(b * SEQ + qrow)) * DMODEL + h * HDIM;
  bf16x8 qf[2];
#pragma unroll
  for (int t = 0; t < 2; ++t) {
    f32x4 a = *reinterpret_cast<const f32x4*>(qptr + t * 32 + g * 8);
    f32x4 c = *reinterpret_cast<const f32x4*>(qptr + t * 32 + g * 8 + 4);
#pragma unroll
    for (int j = 0; j < 4; ++j) {
      qf[t][j]     = (__bf16)(a[j] * QSCALE);
      qf[t][4 + j] = (__bf16)(c[j] * QSCALE);
    }
  }

  float m_run[4], l_run[4];
  f32x4 oacc[4];
#pragma unroll
  for (int j = 0; j < 4; ++j) {
    m_run[j] = -1e30f; l_run[j] = 0.f;
    oacc[j] = (f32x4){0.f, 0.f, 0.f, 0.f};
  }

  const float* kbase = K + ((size_t)(b * SEQ)) * DMODEL + h * HDIM;
  const float* vbase = V + ((size_t)(b * SEQ)) * DMODEL + h * HDIM;

  // staging roles (512 threads)
  const int sk_key0 = tid >> 4;          // K: e=0 key (0..31)
  const int sk_key1 = 32 + (tid >> 4);   // K: e=1 key (32..63)
  const int sk_d4   = tid & 15;          // K: float4 index in 64 dims
  const int sv_d    = tid & 63;          // V: dim (0..63)
  const int sv_ko   = tid >> 6;          // V: key-octet (0..7)

  // --- prologue: stage chunk 0 into buf 0 ---
  {
    f32x4 k0 = *reinterpret_cast<const f32x4*>(
        kbase + (size_t)sk_key0 * DMODEL + sk_d4 * 4);
    f32x4 k1 = *reinterpret_cast<const f32x4*>(
        kbase + (size_t)sk_key1 * DMODEL + sk_d4 * 4);
    bf16x4 kb0, kb1;
#pragma unroll
    for (int j = 0; j < 4; ++j) { kb0[j] = (__bf16)k0[j]; kb1[j] = (__bf16)k1[j]; }
    *reinterpret_cast<bf16x4*>(&Ks[0][sk_key0][sk_d4 * 4]) = kb0;
    *reinterpret_cast<bf16x4*>(&Ks[0][sk_key1][sk_d4 * 4]) = kb1;
    bf16x8 vb;
#pragma unroll
    for (int i = 0; i < 8; ++i)
      vb[i] = (__bf16)vbase[(size_t)(8 * sv_ko + i) * DMODEL + sv_d];
    *reinterpret_cast<bf16x8*>(&Vt[0][sv_d][8 * sv_ko]) = vb;
  }
  __syncthreads();

  for (int c = 0; c < NCHUNK; ++c) {
    const int cur = c & 1;
    const bool pf = (c + 1 < NCHUNK);
    const int k0n = (c + 1) * KVBLK;

    // --- issue global loads for chunk c+1 (converted + written after compute) ---
    f32x4 kp0, kp1; float vp[8];
    if (pf) {
      kp0 = *reinterpret_cast<const f32x4*>(
          kbase + (size_t)(k0n + sk_key0) * DMODEL + sk_d4 * 4);
      kp1 = *reinterpret_cast<const f32x4*>(
          kbase + (size_t)(k0n + sk_key1) * DMODEL + sk_d4 * 4);
#pragma unroll
      for (int i = 0; i < 8; ++i)
        vp[i] = vbase[(size_t)(k0n + 8 * sv_ko + i) * DMODEL + sv_d];
    }

    // --- QK^T: four 16-key tiles ---
    f32x4 sacc[4];
    __builtin_amdgcn_s_setprio(1);
#pragma unroll
    for (int c4 = 0; c4 < 4; ++c4) {
      bf16x8 bk0 = *reinterpret_cast<const bf16x8*>(&Ks[cur][16 * c4 + lr][g * 8]);
      bf16x8 bk1 = *reinterpret_cast<const bf16x8*>(&Ks[cur][16 * c4 + lr][32 + g * 8]);
      f32x4 a = (f32x4){0.f, 0.f, 0.f, 0.f};
      a = __builtin_amdgcn_mfma_f32_16x16x32_bf16(qf[0], bk0, a, 0, 0, 0);
      a = __builtin_amdgcn_mfma_f32_16x16x32_bf16(qf[1], bk1, a, 0, 0, 0);
      sacc[c4] = a;
    }
    __builtin_amdgcn_s_setprio(0);

    // --- chunk-wide row max (64 keys) + rescale once per chunk ---
#pragma unroll
    for (int j = 0; j < 4; ++j) {
      float mn = fmaxf(fmaxf(sacc[0][j], sacc[1][j]), fmaxf(sacc[2][j], sacc[3][j]));
#pragma unroll
      for (int msk = 1; msk < 16; msk <<= 1) mn = fmaxf(mn, __shfl_xor(mn, msk, 64));
      float mu = fmaxf(m_run[j], mn);
      float al = __builtin_amdgcn_exp2f(m_run[j] - mu);
      m_run[j] = mu;
      l_run[j] *= al;
#pragma unroll
      for (int n = 0; n < 4; ++n) oacc[n][j] *= al;
    }

    // --- two PV halves of 32 keys (P via per-wave LDS transpose) ---
    float psum[4] = {0.f, 0.f, 0.f, 0.f};
#pragma unroll
    for (int kc = 0; kc < 2; ++kc) {
#pragma unroll
      for (int j = 0; j < 4; ++j) {
        float p0 = __builtin_amdgcn_exp2f(sacc[2 * kc][j] - m_run[j]);
        float p1 = __builtin_amdgcn_exp2f(sacc[2 * kc + 1][j] - m_run[j]);
        psum[j] += p0 + p1;
        Pl[wave][g * 4 + j][lr]      = (__bf16)p0;
        Pl[wave][g * 4 + j][16 + lr] = (__bf16)p1;
      }
      // wave-synchronous: drain our own ds_writes before cross-lane read
      asm volatile("s_waitcnt lgkmcnt(0)" ::: "memory");
      bf16x8 pa = *reinterpret_cast<const bf16x8*>(&Pl[wave][lr][g * 8]);
      __builtin_amdgcn_s_setprio(1);
#pragma unroll
      for (int n = 0; n < 4; ++n) {
        bf16x8 bv = *reinterpret_cast<const bf16x8*>(
            &Vt[cur][16 * n + lr][g * 8 + 32 * kc]);
        oacc[n] = __builtin_amdgcn_mfma_f32_16x16x32_bf16(pa, bv, oacc[n], 0, 0, 0);
      }
      __builtin_amdgcn_s_setprio(0);
    }
#pragma unroll
    for (int j = 0; j < 4; ++j) {
      float ps = psum[j];
#pragma unroll
      for (int msk = 1; msk < 16; msk <<= 1) ps += __shfl_xor(ps, msk, 64);
      l_run[j] += ps;
    }

    // --- write prefetched chunk into the other buffer ---
    if (pf) {
      const int nb = cur ^ 1;
      bf16x4 kb0, kb1;
#pragma unroll
      for (int j = 0; j < 4; ++j) { kb0[j] = (__bf16)kp0[j]; kb1[j] = (__bf16)kp1[j]; }
      *reinterpret_cast<bf16x4*>(&Ks[nb][sk_key0][sk_d4 * 4]) = kb0;
      *reinterpret_cast<bf16x4*>(&Ks[nb][sk_key1][sk_d4 * 4]) = kb1;
      bf16x8 vb;
#pragma unroll
      for (int i = 0; i < 8; ++i) vb[i] = (__bf16)vp[i];
      *reinterpret_cast<bf16x8*>(&Vt[nb][sv_d][8 * sv_ko]) = vb;
    }
    __syncthreads();
  }

  // --- normalize + store bf16 attention output ---
#pragma unroll
  for (int j = 0; j < 4; ++j) {
    float inv = 1.0f / l_run[j];
    int row = q0 + wave * 16 + g * 4 + j;
    __bf16* optr = O + ((size_t)(b * SEQ + row)) * DMODEL + h * HDIM;
#pragma unroll
    for (int n = 0; n < 4; ++n) optr[n * 16 + lr] = (__bf16)(oacc[n][j] * inv);
  }
}

// ---------------------------------------------------------------------------
// FC: Y[M=4096][N=1024] = X(bf16) @ W^T(fp32->bf16) + bias, fp32 out.
// 128x128 tile, 4 waves (2x2), each wave 64x64 via 4x4 16x16 fragments.
// ---------------------------------------------------------------------------
__global__ __launch_bounds__(256)
void fc_kernel(const __bf16* __restrict__ X, const float* __restrict__ W,
               const float* __restrict__ bias, float* __restrict__ Y) {
  const int n0 = blockIdx.x * 128;
  const int m0 = blockIdx.y * 128;
  const int tid = threadIdx.x;
  const int wave = tid >> 6, lane = tid & 63;
  const int g = lane >> 4, lr = lane & 15;
  const int wm = wave >> 1, wn = wave & 1;

  __shared__ __bf16 As[128][40];   // [m][k] bf16, +8 pad
  __shared__ __bf16 Bs[128][40];   // [n][k] bf16 (B = W^T staged as W rows)

  f32x4 acc[4][4];
#pragma unroll
  for (int i = 0; i < 4; ++i)
#pragma unroll
    for (int j = 0; j < 4; ++j) acc[i][j] = (f32x4){0.f, 0.f, 0.f, 0.f};

  float bv[4];
#pragma unroll
  for (int j = 0; j < 4; ++j) bv[j] = bias[n0 + wn * 64 + 16 * j + lr];

  for (int kk = 0; kk < DMODEL; kk += 32) {
    __syncthreads();
    // stage A: 128x32 bf16 from workspace
#pragma unroll
    for (int e = 0; e < 2; ++e) {
      int idx = tid + 256 * e;           // 0..511
      int row = idx >> 2, k8 = idx & 3;
      bf16x8 v = *reinterpret_cast<const bf16x8*>(
          X + (size_t)(m0 + row) * DMODEL + kk + k8 * 8);
      *reinterpret_cast<bf16x8*>(&As[row][k8 * 8]) = v;
    }
    // stage B: 128x32 fp32 W rows -> bf16
#pragma unroll
    for (int e = 0; e < 4; ++e) {
      int idx = tid + 256 * e;           // 0..1023
      int row = idx >> 3, k4 = idx & 7;
      f32x4 wv = *reinterpret_cast<const f32x4*>(
          W + (size_t)(n0 + row) * DMODEL + kk + k4 * 4);
      bf16x4 wb;
#pragma unroll
      for (int j = 0; j < 4; ++j) wb[j] = (__bf16)wv[j];
      *reinterpret_cast<bf16x4*>(&Bs[row][k4 * 4]) = wb;
    }
    __syncthreads();

    bf16x8 af[4], bfr[4];
#pragma unroll
    for (int i = 0; i < 4; ++i)
      af[i] = *reinterpret_cast<const bf16x8*>(&As[wm * 64 + 16 * i + lr][g * 8]);
#pragma unroll
    for (int j = 0; j < 4; ++j)
      bfr[j] = *reinterpret_cast<const bf16x8*>(&Bs[wn * 64 + 16 * j + lr][g * 8]);
#pragma unroll
    for (int i = 0; i < 4; ++i)
#pragma unroll
      for (int j = 0; j < 4; ++j)
        acc[i][j] = __builtin_amdgcn_mfma_f32_16x16x32_bf16(af[i], bfr[j], acc[i][j], 0, 0, 0);
  }

#pragma unroll
  for (int i = 0; i < 4; ++i) {
    int m = m0 + wm * 64 + 16 * i + g * 4;
#pragma unroll
    for (int j = 0; j < 4; ++j) {
      int n = n0 + wn * 64 + 16 * j + lr;
      float* yp = Y + (size_t)m * DMODEL + n;
#pragma unroll
      for (int r = 0; r < 4; ++r) yp[(size_t)r * DMODEL] = acc[i][j][r] + bv[j];
    }
  }
}

extern "C" void kernel_launch(void* const* d_in, const int* in_sizes, int n_in,
                              void* d_out, int out_size, void* d_ws, size_t ws_size,
                              hipStream_t stream) {
  const float* q    = (const float*)d_in[0];
  const float* k    = (const float*)d_in[1];
  const float* v    = (const float*)d_in[2];
  const float* w    = (const float*)d_in[3];
  const float* bias = (const float*)d_in[4];
  float* out = (float*)d_out;
  __bf16* O = (__bf16*)d_ws;   // 4096*1024 bf16 = 8 MB attention output

  dim3 gridA(SEQ / 128, NHEADS, BATCH);
  attn_kernel<<<gridA, 512, 0, stream>>>(q, k, v, O);

  dim3 gridF(DMODEL / 128, (BATCH * SEQ) / 128);
  fc_kernel<<<gridF, 256, 0, stream>>>(O, w, bias, out);
}

// Round 7
// 118.583 us; speedup vs baseline: 1.8797x; 1.2055x over previous
//
#include <hip/hip_runtime.h>
#include <hip/hip_bf16.h>

#define BATCH 2
#define SEQ 2048
#define DMODEL 1024
#define NHEADS 16
#define HDIM 64
#define KVBLK 64
#define NCHUNK (SEQ / KVBLK)   // 32

// 0.125 (1/sqrt(64)) * log2(e): logits land directly in exp2 domain
#define QSCALE 0.180336880f
#define DEFER_THR 8.0f

typedef __bf16 bf16x8 __attribute__((ext_vector_type(8)));
typedef __bf16 bf16x4 __attribute__((ext_vector_type(4)));
typedef float f32x4 __attribute__((ext_vector_type(4)));
typedef float f32x16 __attribute__((ext_vector_type(16)));
typedef unsigned int uint2v __attribute__((ext_vector_type(2)));

union B8u { unsigned int u[4]; bf16x8 v; };

__device__ __forceinline__ unsigned int cvt_pk_bf16(float lo, float hi) {
  unsigned int d;
  asm("v_cvt_pk_bf16_f32 %0, %1, %2" : "=v"(d) : "v"(lo), "v"(hi));
  return d;
}

// a' = {a.lo32lanes, b.lo32lanes}; b' = {a.hi32lanes, b.hi32lanes}
__device__ __forceinline__ void permlane32_swap(unsigned &a, unsigned &b) {
  auto r = __builtin_amdgcn_permlane32_swap(a, b, false, false);
  unsigned tmp[2];
  __builtin_memcpy(tmp, &r, 8);
  a = tmp[0]; b = tmp[1];
}

// ---------------------------------------------------------------------------
// Flash attention, 32x32 swapped-operand structure.
// Block = 128 q-rows of one (b,h); 4 waves x 32 q-rows. KVBLK=64.
// S^T = mfma(K, Q)  -> qrow = lane&31 -> in-register softmax (no LDS P).
// O^T = mfma(V^T, P^T) -> P^T B-frag built via cvt_pk + permlane32_swap.
// K/V LDS XOR-swizzled (byte ^= (row&7)<<4), double-buffered, 1 barrier/chunk.
// ---------------------------------------------------------------------------
__global__ __launch_bounds__(256, 3)
void attn_kernel(const float* __restrict__ Q, const float* __restrict__ K,
                 const float* __restrict__ V, __bf16* __restrict__ O) {
  const int b = blockIdx.z, h = blockIdx.y;
  const int q0 = blockIdx.x * 128;
  const int tid = threadIdx.x;
  const int wave = tid >> 6, lane = tid & 63;
  const int l31 = lane & 31, hi = lane >> 5;
  const int ob = hi << 4;                 // 16*hi byte offset within granule row
  const int swz = (l31 & 7) << 4;         // read-side XOR (row&7 == l31&7 for row=32t+l31)

  __shared__ __align__(16) __bf16 Ks[2][64 * 64];  // [buf][key*64 + d], 128B rows
  __shared__ __align__(16) __bf16 Vt[2][64 * 64];  // [buf][dim*64 + key]

  // --- Q fragments: B-operand of swapped QK^T: lane holds Q[qrow=l31][16kd+8hi+j]
  const int qrow = q0 + (wave << 5) + l31;
  const float* qp = Q + ((size_t)(b * SEQ + qrow)) * DMODEL + h * HDIM;
  bf16x8 qf[4];
#pragma unroll
  for (int kd = 0; kd < 4; ++kd) {
    f32x4 a = *reinterpret_cast<const f32x4*>(qp + kd * 16 + hi * 8);
    f32x4 c = *reinterpret_cast<const f32x4*>(qp + kd * 16 + hi * 8 + 4);
#pragma unroll
    for (int j = 0; j < 4; ++j) {
      qf[kd][j]     = (__bf16)(a[j] * QSCALE);
      qf[kd][4 + j] = (__bf16)(c[j] * QSCALE);
    }
  }

  f32x16 oacc0, oacc1;
#pragma unroll
  for (int r = 0; r < 16; ++r) { oacc0[r] = 0.f; oacc1[r] = 0.f; }
  float m_run = -1e30f, l_run = 0.f;

  const float* kbase = K + ((size_t)(b * SEQ)) * DMODEL + h * HDIM;
  const float* vbase = V + ((size_t)(b * SEQ)) * DMODEL + h * HDIM;

  // staging roles (256 threads): K: thread -> (key, dim-quarter); V: (dim, key-16-group)
  const int sk_key = tid >> 2, sk_dq = tid & 3;
  const int sv_dim = tid & 63, sv_kh = tid >> 6;
  const size_t k_off = (size_t)sk_key * DMODEL + sk_dq * 16;
  const int ksw = (sk_key & 7) << 4;
  const int vsw = (sv_dim & 7) << 4;

  f32x4 kp[4];
  float vp[16];

#define STAGE_LOAD(C0)                                                        \
  do {                                                                        \
    const float* kc = kbase + (size_t)(C0) * DMODEL;                          \
    const float* vc = vbase + (size_t)(C0) * DMODEL;                          \
    _Pragma("unroll") for (int i = 0; i < 4; ++i)                             \
        kp[i] = *reinterpret_cast<const f32x4*>(kc + k_off + 4 * i);          \
    _Pragma("unroll") for (int i = 0; i < 16; ++i)                            \
        vp[i] = vc[(size_t)(sv_kh * 16 + i) * DMODEL + sv_dim];               \
  } while (0)

#define STAGE_WRITE(B)                                                        \
  do {                                                                        \
    char* kdst = (char*)(&Ks[B][0]) + sk_key * 128;                           \
    bf16x8 e0, e1;                                                            \
    _Pragma("unroll") for (int j = 0; j < 4; ++j) {                           \
      e0[j] = (__bf16)kp[0][j]; e0[4 + j] = (__bf16)kp[1][j];                 \
      e1[j] = (__bf16)kp[2][j]; e1[4 + j] = (__bf16)kp[3][j];                 \
    }                                                                         \
    *reinterpret_cast<bf16x8*>(kdst + (((sk_dq << 5)) ^ ksw)) = e0;           \
    *reinterpret_cast<bf16x8*>(kdst + (((sk_dq << 5) | 16) ^ ksw)) = e1;      \
    char* vdst = (char*)(&Vt[B][0]) + sv_dim * 128;                           \
    bf16x8 f0, f1;                                                            \
    _Pragma("unroll") for (int i = 0; i < 8; ++i) {                           \
      f0[i] = (__bf16)vp[i]; f1[i] = (__bf16)vp[8 + i];                       \
    }                                                                         \
    *reinterpret_cast<bf16x8*>(vdst + (((sv_kh << 5)) ^ vsw)) = f0;           \
    *reinterpret_cast<bf16x8*>(vdst + (((sv_kh << 5) | 16) ^ vsw)) = f1;      \
  } while (0)

  // prologue: chunk 0 -> buf 0
  STAGE_LOAD(0);
  STAGE_WRITE(0);
  __syncthreads();

  for (int c = 0; c < NCHUNK; ++c) {
    const int cur = c & 1;
    const bool pf = (c + 1 < NCHUNK);
    if (pf) STAGE_LOAD((c + 1) * KVBLK);

    const char* kb = (const char*)(&Ks[cur][0]);
    const char* vb = (const char*)(&Vt[cur][0]);

    // --- QK^T swapped: S^T[key][qrow]; lane -> qrow=l31, 32 keys in regs ---
    f32x16 s0, s1;
#pragma unroll
    for (int r = 0; r < 16; ++r) { s0[r] = 0.f; s1[r] = 0.f; }
    __builtin_amdgcn_s_setprio(1);
#pragma unroll
    for (int kd = 0; kd < 4; ++kd) {
      bf16x8 a0 = *reinterpret_cast<const bf16x8*>(
          kb + l31 * 128 + (((kd << 5) | ob) ^ swz));
      bf16x8 a1 = *reinterpret_cast<const bf16x8*>(
          kb + (32 + l31) * 128 + (((kd << 5) | ob) ^ swz));
      s0 = __builtin_amdgcn_mfma_f32_32x32x16_bf16(a0, qf[kd], s0, 0, 0, 0);
      s1 = __builtin_amdgcn_mfma_f32_32x32x16_bf16(a1, qf[kd], s1, 0, 0, 0);
    }
    __builtin_amdgcn_s_setprio(0);

    // --- row max (in-register tree + one cross-half exchange) ---
    float m8[8];
#pragma unroll
    for (int r = 0; r < 8; ++r)
      m8[r] = fmaxf(fmaxf(s0[r], s0[r + 8]), fmaxf(s1[r], s1[r + 8]));
    float pm = fmaxf(fmaxf(fmaxf(m8[0], m8[1]), fmaxf(m8[2], m8[3])),
                     fmaxf(fmaxf(m8[4], m8[5]), fmaxf(m8[6], m8[7])));
    pm = fmaxf(pm, __shfl_xor(pm, 32, 64));

    // --- defer-max rescale (T13): skip O-rescale while max growth <= THR ---
    if (!__all(pm <= m_run + DEFER_THR)) {
      float mu = fmaxf(m_run, pm);
      float al = __builtin_amdgcn_exp2f(m_run - mu);
      m_run = mu;
      l_run *= al;
#pragma unroll
      for (int r = 0; r < 16; ++r) { oacc0[r] *= al; oacc1[r] *= al; }
    }

    // --- P = exp2(S - m), in place ---
#pragma unroll
    for (int r = 0; r < 16; ++r) {
      s0[r] = __builtin_amdgcn_exp2f(s0[r] - m_run);
      s1[r] = __builtin_amdgcn_exp2f(s1[r] - m_run);
    }
    // row sum
    float t8[8];
#pragma unroll
    for (int r = 0; r < 8; ++r)
      t8[r] = (s0[r] + s0[r + 8]) + (s1[r] + s1[r + 8]);
    float ts = ((t8[0] + t8[1]) + (t8[2] + t8[3])) +
               ((t8[4] + t8[5]) + (t8[6] + t8[7]));
    ts += __shfl_xor(ts, 32, 64);
    l_run += ts;

    // --- pack P^T B-frags: 16 cvt_pk + 8 permlane32_swap ---
    // lane holds s[r] = P[key=(r&3)+8(r>>2)+4hi + 32*(s1?)][qrow=l31].
    // B-frag word w for step ks needs keys {16ks+8hi+2w, +1}:
    //   swap(lo,h): lo' = {lo.lo, h.lo} (words 0/1), h' = {lo.hi, h.hi} (words 2/3)
    B8u pfr[4];
#pragma unroll
    for (int ks = 0; ks < 4; ++ks) {
      f32x16 ps = (ks < 2) ? s0 : s1;
      const int r0 = (ks & 1) * 8;
      unsigned lo0 = cvt_pk_bf16(ps[r0 + 0], ps[r0 + 1]);
      unsigned lo1 = cvt_pk_bf16(ps[r0 + 2], ps[r0 + 3]);
      unsigned h0  = cvt_pk_bf16(ps[r0 + 4], ps[r0 + 5]);
      unsigned h1  = cvt_pk_bf16(ps[r0 + 6], ps[r0 + 7]);
      permlane32_swap(lo0, h0);
      permlane32_swap(lo1, h1);
      pfr[ks].u[0] = lo0; pfr[ks].u[1] = lo1;
      pfr[ks].u[2] = h0;  pfr[ks].u[3] = h1;
    }

    // --- PV swapped: O^T[dim][qrow] += V^T[dim][key] * P^T[key][qrow] ---
    __builtin_amdgcn_s_setprio(1);
#pragma unroll
    for (int ks = 0; ks < 4; ++ks) {
      bf16x8 v0 = *reinterpret_cast<const bf16x8*>(
          vb + l31 * 128 + (((ks << 5) | ob) ^ swz));
      bf16x8 v1 = *reinterpret_cast<const bf16x8*>(
          vb + (32 + l31) * 128 + (((ks << 5) | ob) ^ swz));
      oacc0 = __builtin_amdgcn_mfma_f32_32x32x16_bf16(v0, pfr[ks].v, oacc0, 0, 0, 0);
      oacc1 = __builtin_amdgcn_mfma_f32_32x32x16_bf16(v1, pfr[ks].v, oacc1, 0, 0, 0);
    }
    __builtin_amdgcn_s_setprio(0);

    if (pf) STAGE_WRITE(cur ^ 1);
    __syncthreads();
  }

  // --- normalize + store: lane owns qrow=l31; dims = 32dt + 8a + 4hi + 0..3 ---
  const float inv = 1.0f / l_run;
  __bf16* op = O + ((size_t)(b * SEQ + qrow)) * DMODEL + h * HDIM;
#pragma unroll
  for (int dt = 0; dt < 2; ++dt) {
    f32x16 oa = dt ? oacc1 : oacc0;
#pragma unroll
    for (int a = 0; a < 4; ++a) {
      uint2v w;
      w[0] = cvt_pk_bf16(oa[4 * a + 0] * inv, oa[4 * a + 1] * inv);
      w[1] = cvt_pk_bf16(oa[4 * a + 2] * inv, oa[4 * a + 3] * inv);
      *reinterpret_cast<uint2v*>((char*)op + (dt * 32 + a * 8 + hi * 4) * 2) = w;
    }
  }
#undef STAGE_LOAD
#undef STAGE_WRITE
}

// ---------------------------------------------------------------------------
// FC: Y[M=4096][N=1024] = X(bf16) @ W^T(fp32->bf16) + bias, fp32 out.
// 128x128 tile, 4 waves (2x2), each wave 64x64 via 4x4 16x16 fragments.
// ---------------------------------------------------------------------------
__global__ __launch_bounds__(256)
void fc_kernel(const __bf16* __restrict__ X, const float* __restrict__ W,
               const float* __restrict__ bias, float* __restrict__ Y) {
  const int n0 = blockIdx.x * 128;
  const int m0 = blockIdx.y * 128;
  const int tid = threadIdx.x;
  const int wave = tid >> 6, lane = tid & 63;
  const int g = lane >> 4, lr = lane & 15;
  const int wm = wave >> 1, wn = wave & 1;

  __shared__ __bf16 As[128][40];   // [m][k] bf16, +8 pad
  __shared__ __bf16 Bs[128][40];   // [n][k] bf16 (B = W^T staged as W rows)

  f32x4 acc[4][4];
#pragma unroll
  for (int i = 0; i < 4; ++i)
#pragma unroll
    for (int j = 0; j < 4; ++j) acc[i][j] = (f32x4){0.f, 0.f, 0.f, 0.f};

  float bv[4];
#pragma unroll
  for (int j = 0; j < 4; ++j) bv[j] = bias[n0 + wn * 64 + 16 * j + lr];

  for (int kk = 0; kk < DMODEL; kk += 32) {
    __syncthreads();
#pragma unroll
    for (int e = 0; e < 2; ++e) {
      int idx = tid + 256 * e;
      int row = idx >> 2, k8 = idx & 3;
      bf16x8 v = *reinterpret_cast<const bf16x8*>(
          X + (size_t)(m0 + row) * DMODEL + kk + k8 * 8);
      *reinterpret_cast<bf16x8*>(&As[row][k8 * 8]) = v;
    }
#pragma unroll
    for (int e = 0; e < 4; ++e) {
      int idx = tid + 256 * e;
      int row = idx >> 3, k4 = idx & 7;
      f32x4 wv = *reinterpret_cast<const f32x4*>(
          W + (size_t)(n0 + row) * DMODEL + kk + k4 * 4);
      bf16x4 wb;
#pragma unroll
      for (int j = 0; j < 4; ++j) wb[j] = (__bf16)wv[j];
      *reinterpret_cast<bf16x4*>(&Bs[row][k4 * 4]) = wb;
    }
    __syncthreads();

    bf16x8 af[4], bfr[4];
#pragma unroll
    for (int i = 0; i < 4; ++i)
      af[i] = *reinterpret_cast<const bf16x8*>(&As[wm * 64 + 16 * i + lr][g * 8]);
#pragma unroll
    for (int j = 0; j < 4; ++j)
      bfr[j] = *reinterpret_cast<const bf16x8*>(&Bs[wn * 64 + 16 * j + lr][g * 8]);
#pragma unroll
    for (int i = 0; i < 4; ++i)
#pragma unroll
      for (int j = 0; j < 4; ++j)
        acc[i][j] = __builtin_amdgcn_mfma_f32_16x16x32_bf16(af[i], bfr[j], acc[i][j], 0, 0, 0);
  }

#pragma unroll
  for (int i = 0; i < 4; ++i) {
    int m = m0 + wm * 64 + 16 * i + g * 4;
#pragma unroll
    for (int j = 0; j < 4; ++j) {
      int n = n0 + wn * 64 + 16 * j + lr;
      float* yp = Y + (size_t)m * DMODEL + n;
#pragma unroll
      for (int r = 0; r < 4; ++r) yp[(size_t)r * DMODEL] = acc[i][j][r] + bv[j];
    }
  }
}

extern "C" void kernel_launch(void* const* d_in, const int* in_sizes, int n_in,
                              void* d_out, int out_size, void* d_ws, size_t ws_size,
                              hipStream_t stream) {
  const float* q    = (const float*)d_in[0];
  const float* k    = (const float*)d_in[1];
  const float* v    = (const float*)d_in[2];
  const float* w    = (const float*)d_in[3];
  const float* bias = (const float*)d_in[4];
  float* out = (float*)d_out;
  __bf16* O = (__bf16*)d_ws;   // 4096*1024 bf16 = 8 MB attention output

  dim3 gridA(SEQ / 128, NHEADS, BATCH);
  attn_kernel<<<gridA, 256, 0, stream>>>(q, k, v, O);

  dim3 gridF(DMODEL / 128, (BATCH * SEQ) / 128);
  fc_kernel<<<gridF, 256, 0, stream>>>(O, w, bias, out);
}